// Round 1
// baseline (205.309 us; speedup 1.0000x reference)
//
#include <hip/hip_runtime.h>
#include <math.h>

// Problem constants (B=16, C=8, H=512, W=512)
#define HW      262144      // 512*512
#define HWQ     65536       // HW/4  (channel stride in float4 units)
#define CHW     2097152     // 8*HW  (batch stride in floats)
#define NGROUPS 1048576     // B*HW/4 total float4 pixel-groups
#define NBLOCKS 1024
#define NTHREADS 256
#define TOTAL_PX 4194304.0f // B*H*W

__global__ __launch_bounds__(NTHREADS)
void argmax_hist_kernel(const float* __restrict__ masks,
                        unsigned int* __restrict__ partial) {
    const int tid = threadIdx.x;
    int cnt[8] = {0, 0, 0, 0, 0, 0, 0, 0};

    // grid-stride over float4 groups; exact division: 4 iterations/thread
    for (int g = blockIdx.x * NTHREADS + tid; g < NGROUPS; g += NBLOCKS * NTHREADS) {
        const int b   = g >> 16;          // g / (HW/4)
        const int hw4 = (g & 65535) << 2; // (g % (HW/4)) * 4
        const float4* p = (const float4*)(masks + (size_t)b * CHW + hw4);

        float4 v = p[0];
        float bv0 = v.x, bv1 = v.y, bv2 = v.z, bv3 = v.w;
        int   bi0 = 0,   bi1 = 0,   bi2 = 0,   bi3 = 0;
        #pragma unroll
        for (int c = 1; c < 8; ++c) {
            float4 u = p[(size_t)c * HWQ];
            // strict > : first occurrence of max wins (jnp.argmax semantics)
            bi0 = (u.x > bv0) ? c : bi0;  bv0 = (u.x > bv0) ? u.x : bv0;
            bi1 = (u.y > bv1) ? c : bi1;  bv1 = (u.y > bv1) ? u.y : bv1;
            bi2 = (u.z > bv2) ? c : bi2;  bv2 = (u.z > bv2) ? u.z : bv2;
            bi3 = (u.w > bv3) ? c : bi3;  bv3 = (u.w > bv3) ? u.w : bv3;
        }
        // predicated histogram update (no dynamic register indexing)
        #pragma unroll
        for (int k = 0; k < 8; ++k) {
            cnt[k] += (bi0 == k) + (bi1 == k) + (bi2 == k) + (bi3 == k);
        }
    }

    // wave-level reduction (wave = 64 lanes on gfx950)
    #pragma unroll
    for (int k = 0; k < 8; ++k) {
        #pragma unroll
        for (int off = 32; off >= 1; off >>= 1) {
            cnt[k] += __shfl_down(cnt[k], off, 64);
        }
    }

    __shared__ int lds[32];  // [4 waves][8 classes]
    const int lane = tid & 63;
    const int wid  = tid >> 6;
    if (lane == 0) {
        #pragma unroll
        for (int k = 0; k < 8; ++k) lds[wid * 8 + k] = cnt[k];
    }
    __syncthreads();
    if (tid < 8) {
        // every block writes all 8 of its slots unconditionally (ws is poisoned)
        unsigned int s = (unsigned int)(lds[tid] + lds[8 + tid] + lds[16 + tid] + lds[24 + tid]);
        partial[blockIdx.x * 8 + tid] = s;
    }
}

__global__ __launch_bounds__(64)
void finalize_kernel(const unsigned int* __restrict__ partial,
                     const float* __restrict__ prev,
                     float* __restrict__ out) {
    __shared__ float s[64];
    const int t = threadIdx.x;      // 64 threads
    const int c = t & 7;
    const int r = t >> 3;

    unsigned int sum = 0;
    for (int row = r; row < NBLOCKS; row += 8) {
        sum += partial[row * 8 + c];
    }
    s[t] = (float)sum;              // exact: < 2^24
    __syncthreads();

    if (t < 8) {
        float h = 0.0f;
        #pragma unroll
        for (int k = 0; k < 8; ++k) h += s[t + 8 * k];   // exact: <= 4194304
        float dist = prev[t] * 0.99f + 0.01f * h / TOTAL_PX;
        out[1 + t] = dist;
        float d = (dist - 0.125f) / 0.875f;
        s[t] = d * d;
    }
    __syncthreads();
    if (t == 0) {
        float acc = 0.0f;
        #pragma unroll
        for (int k = 0; k < 8; ++k) acc += s[k];
        out[0] = sqrtf(acc);
    }
}

extern "C" void kernel_launch(void* const* d_in, const int* in_sizes, int n_in,
                              void* d_out, int out_size, void* d_ws, size_t ws_size,
                              hipStream_t stream) {
    const float* masks = (const float*)d_in[0];   // [16,8,512,512] fp32
    const float* prev  = (const float*)d_in[1];   // [8] fp32
    float* out = (float*)d_out;                   // [9]: balance, dist[0..7]
    unsigned int* partial = (unsigned int*)d_ws;  // [1024][8] u32 = 32 KB

    argmax_hist_kernel<<<NBLOCKS, NTHREADS, 0, stream>>>(masks, partial);
    finalize_kernel<<<1, 64, 0, stream>>>(partial, prev, out);
}

// Round 2
// 198.914 us; speedup vs baseline: 1.0322x; 1.0322x over previous
//
#include <hip/hip_runtime.h>
#include <math.h>

// Problem constants (B=16, C=8, H=512, W=512)
#define HW        262144      // 512*512
#define HWQ       65536       // HW/4  (channel stride in float4 units)
#define CHW       2097152     // 8*HW  (batch stride in floats)
#define NGROUPS   1048576     // B*HW/4 total float4 pixel-groups
#define NBLOCKS   2048
#define NTHREADS  256
#define GSTRIDE   524288      // NBLOCKS*NTHREADS (groups per pass)
#define TOTAL_PX  4194304.0f  // B*H*W

// 2048 blocks x 256 thr = 8 blocks/CU = 32 waves/CU (max occupancy) if VGPR<=64.
// Each thread handles exactly 2 float4 pixel-groups (no bounds check needed:
// 2048*256*2 == NGROUPS exactly).
__global__ __launch_bounds__(NTHREADS, 8)
void argmax_hist_kernel(const float* __restrict__ masks,
                        unsigned int* __restrict__ partial) {
    const int tid = threadIdx.x;
    int cnt[8] = {0, 0, 0, 0, 0, 0, 0, 0};

    const int gbase = blockIdx.x * NTHREADS + tid;

    #pragma unroll
    for (int it = 0; it < 2; ++it) {
        const int g   = gbase + it * GSTRIDE;
        const int b   = g >> 16;          // g / (HW/4)
        const int hw4 = (g & 65535) << 2; // (g % (HW/4)) * 4
        const float4* p = (const float4*)(masks + (size_t)b * CHW + hw4);

        // 8 independent 16B loads (one per channel) — all issued before use.
        float4 v0 = p[0];
        float4 v1 = p[1 * HWQ];
        float4 v2 = p[2 * HWQ];
        float4 v3 = p[3 * HWQ];
        float4 v4 = p[4 * HWQ];
        float4 v5 = p[5 * HWQ];
        float4 v6 = p[6 * HWQ];
        float4 v7 = p[7 * HWQ];

        float bv0 = v0.x, bv1 = v0.y, bv2 = v0.z, bv3 = v0.w;
        int   bi0 = 0,    bi1 = 0,    bi2 = 0,    bi3 = 0;

        // strict > : first occurrence of max wins (jnp.argmax semantics)
        #define STEP(vv, c)                                                   \
            bi0 = ((vv).x > bv0) ? (c) : bi0;  bv0 = ((vv).x > bv0) ? (vv).x : bv0; \
            bi1 = ((vv).y > bv1) ? (c) : bi1;  bv1 = ((vv).y > bv1) ? (vv).y : bv1; \
            bi2 = ((vv).z > bv2) ? (c) : bi2;  bv2 = ((vv).z > bv2) ? (vv).z : bv2; \
            bi3 = ((vv).w > bv3) ? (c) : bi3;  bv3 = ((vv).w > bv3) ? (vv).w : bv3;
        STEP(v1, 1) STEP(v2, 2) STEP(v3, 3) STEP(v4, 4)
        STEP(v5, 5) STEP(v6, 6) STEP(v7, 7)
        #undef STEP

        // predicated histogram update (no dynamic register indexing)
        #pragma unroll
        for (int k = 0; k < 8; ++k) {
            cnt[k] += (bi0 == k) + (bi1 == k) + (bi2 == k) + (bi3 == k);
        }
    }

    // wave-level reduction (wave = 64 lanes on gfx950)
    #pragma unroll
    for (int k = 0; k < 8; ++k) {
        #pragma unroll
        for (int off = 32; off >= 1; off >>= 1) {
            cnt[k] += __shfl_down(cnt[k], off, 64);
        }
    }

    __shared__ int lds[32];  // [4 waves][8 classes]
    const int lane = tid & 63;
    const int wid  = tid >> 6;
    if (lane == 0) {
        #pragma unroll
        for (int k = 0; k < 8; ++k) lds[wid * 8 + k] = cnt[k];
    }
    __syncthreads();
    if (tid < 8) {
        // every block writes all 8 of its slots unconditionally (ws is poisoned)
        unsigned int s = (unsigned int)(lds[tid] + lds[8 + tid] + lds[16 + tid] + lds[24 + tid]);
        partial[blockIdx.x * 8 + tid] = s;
    }
}

__global__ __launch_bounds__(256)
void finalize_kernel(const unsigned int* __restrict__ partial,
                     const float* __restrict__ prev,
                     float* __restrict__ out) {
    __shared__ float s[256];
    const int t = threadIdx.x;      // 256 threads
    const int c = t & 7;            // class
    const int j = t >> 3;           // 0..31 row-group

    unsigned int sum = 0;
    for (int row = j; row < NBLOCKS; row += 32) {   // 64 iterations
        sum += partial[row * 8 + c];
    }
    s[t] = (float)sum;              // exact: <= 2^22
    __syncthreads();

    if (t < 8) {
        float h = 0.0f;
        #pragma unroll
        for (int k = 0; k < 32; ++k) h += s[t + 8 * k];   // exact: <= 4194304
        float dist = prev[t] * 0.99f + 0.01f * h / TOTAL_PX;
        out[1 + t] = dist;
        float d = (dist - 0.125f) / 0.875f;
        s[t] = d * d;
    }
    __syncthreads();
    if (t == 0) {
        float acc = 0.0f;
        #pragma unroll
        for (int k = 0; k < 8; ++k) acc += s[k];
        out[0] = sqrtf(acc);
    }
}

extern "C" void kernel_launch(void* const* d_in, const int* in_sizes, int n_in,
                              void* d_out, int out_size, void* d_ws, size_t ws_size,
                              hipStream_t stream) {
    const float* masks = (const float*)d_in[0];   // [16,8,512,512] fp32
    const float* prev  = (const float*)d_in[1];   // [8] fp32
    float* out = (float*)d_out;                   // [9]: balance, dist[0..7]
    unsigned int* partial = (unsigned int*)d_ws;  // [2048][8] u32 = 64 KB

    argmax_hist_kernel<<<NBLOCKS, NTHREADS, 0, stream>>>(masks, partial);
    finalize_kernel<<<1, 256, 0, stream>>>(partial, prev, out);
}

// Round 3
// 197.204 us; speedup vs baseline: 1.0411x; 1.0087x over previous
//
#include <hip/hip_runtime.h>
#include <math.h>

// Problem constants (B=16, C=8, H=512, W=512)
#define HW        262144      // 512*512
#define HWQ       65536       // HW/4  (channel stride in float4 units)
#define CHW       2097152     // 8*HW  (batch stride in floats)
#define NGROUPS   1048576     // B*HW/4 total float4 pixel-groups
#define NBLOCKS   4096
#define NTHREADS  256
#define TOTAL_PX  4194304.0f  // B*H*W

typedef float v4f __attribute__((ext_vector_type(4)));

// 4096 blocks x 256 threads x 1 float4-group each == NGROUPS exactly.
// Leanest streaming form: 8 independent nontemporal dwordx4 loads, argmax
// compare-select chain, then ballot-based wave histogram (v_cmp + s_bcnt1,
// no per-thread counters, no ds_bpermute shuffles).
__global__ __launch_bounds__(NTHREADS, 8)
void argmax_hist_kernel(const float* __restrict__ masks,
                        unsigned int* __restrict__ partial) {
    const int tid = threadIdx.x;
    const int g   = blockIdx.x * NTHREADS + tid;  // 0..NGROUPS-1
    const int b   = g >> 16;                       // g / (HW/4)
    const int hw4 = (g & 65535) << 2;              // (g % (HW/4)) * 4
    const v4f* p = (const v4f*)(masks + (size_t)b * CHW + hw4);

    // 8 independent 16B nontemporal loads (single-use streaming data)
    v4f v0 = __builtin_nontemporal_load(p + 0 * HWQ);
    v4f v1 = __builtin_nontemporal_load(p + 1 * HWQ);
    v4f v2 = __builtin_nontemporal_load(p + 2 * HWQ);
    v4f v3 = __builtin_nontemporal_load(p + 3 * HWQ);
    v4f v4 = __builtin_nontemporal_load(p + 4 * HWQ);
    v4f v5 = __builtin_nontemporal_load(p + 5 * HWQ);
    v4f v6 = __builtin_nontemporal_load(p + 6 * HWQ);
    v4f v7 = __builtin_nontemporal_load(p + 7 * HWQ);

    float bv0 = v0.x, bv1 = v0.y, bv2 = v0.z, bv3 = v0.w;
    int   bi0 = 0,    bi1 = 0,    bi2 = 0,    bi3 = 0;

    // strict > : first occurrence of max wins (jnp.argmax semantics)
    #define STEP(vv, c)                                                         \
        bi0 = ((vv).x > bv0) ? (c) : bi0;  bv0 = ((vv).x > bv0) ? (vv).x : bv0; \
        bi1 = ((vv).y > bv1) ? (c) : bi1;  bv1 = ((vv).y > bv1) ? (vv).y : bv1; \
        bi2 = ((vv).z > bv2) ? (c) : bi2;  bv2 = ((vv).z > bv2) ? (vv).z : bv2; \
        bi3 = ((vv).w > bv3) ? (c) : bi3;  bv3 = ((vv).w > bv3) ? (vv).w : bv3;
    STEP(v1, 1) STEP(v2, 2) STEP(v3, 3) STEP(v4, 4)
    STEP(v5, 5) STEP(v6, 6) STEP(v7, 7)
    #undef STEP

    // ballot histogram: wave-uniform counts via v_cmp -> s_bcnt1 (scalar adds)
    const int lane = tid & 63;
    const int wid  = tid >> 6;
    __shared__ int lds[32];  // [4 waves][8 classes]
    #pragma unroll
    for (int k = 0; k < 8; ++k) {
        int c = __popcll(__ballot(bi0 == k)) + __popcll(__ballot(bi1 == k))
              + __popcll(__ballot(bi2 == k)) + __popcll(__ballot(bi3 == k));
        if (lane == 0) lds[wid * 8 + k] = c;
    }
    __syncthreads();
    if (tid < 8) {
        // every block writes all 8 of its slots unconditionally (ws is poisoned)
        unsigned int s = (unsigned int)(lds[tid] + lds[8 + tid] + lds[16 + tid] + lds[24 + tid]);
        partial[blockIdx.x * 8 + tid] = s;
    }
}

__global__ __launch_bounds__(256)
void finalize_kernel(const unsigned int* __restrict__ partial,
                     const float* __restrict__ prev,
                     float* __restrict__ out) {
    __shared__ float s[256];
    const int t = threadIdx.x;      // 256 threads
    const int c = t & 7;            // class
    const int j = t >> 3;           // 0..31 row-group

    unsigned int sum = 0;
    for (int row = j; row < NBLOCKS; row += 32) {   // 128 iterations
        sum += partial[row * 8 + c];
    }
    s[t] = (float)sum;              // exact: <= 2^22
    __syncthreads();

    if (t < 8) {
        float h = 0.0f;
        #pragma unroll
        for (int k = 0; k < 32; ++k) h += s[t + 8 * k];   // exact: <= 4194304
        float dist = prev[t] * 0.99f + 0.01f * h / TOTAL_PX;
        out[1 + t] = dist;
        float d = (dist - 0.125f) / 0.875f;
        s[t] = d * d;
    }
    __syncthreads();
    if (t == 0) {
        float acc = 0.0f;
        #pragma unroll
        for (int k = 0; k < 8; ++k) acc += s[k];
        out[0] = sqrtf(acc);
    }
}

extern "C" void kernel_launch(void* const* d_in, const int* in_sizes, int n_in,
                              void* d_out, int out_size, void* d_ws, size_t ws_size,
                              hipStream_t stream) {
    const float* masks = (const float*)d_in[0];   // [16,8,512,512] fp32
    const float* prev  = (const float*)d_in[1];   // [8] fp32
    float* out = (float*)d_out;                   // [9]: balance, dist[0..7]
    unsigned int* partial = (unsigned int*)d_ws;  // [4096][8] u32 = 128 KB

    argmax_hist_kernel<<<NBLOCKS, NTHREADS, 0, stream>>>(masks, partial);
    finalize_kernel<<<1, 256, 0, stream>>>(partial, prev, out);
}